// Round 6
// baseline (117.051 us; speedup 1.0000x reference)
//
#include <hip/hip_runtime.h>

// SparseNeuralNetwork: 256 independent sub-nets j = i*16 + o (i,o in [0,16)).
//   layer0: v[k] = relu(W0[16j+k, i] * x[b,i] + b0[16j+k]),   k in [0,16)
//   layer1: u[m] = relu(b1[8j+m] + sum_k W1[8j+m, 16j+k] * v[k]), m in [0,8)
//   out[b,o] = b2[o] + sum_i sum_m W2[o, 8j+m] * u[m]
//
// R6: R2/R4/R5 all plateau ~34-38us kernel time because the inner loop
// re-fetches weights every iteration (LDS broadcast or SMEM chunks) and runs
// latency-bound. Fix: wave = one (o,i) slot; its 176 weights live in VGPRs
// for the wave's whole life (one-time uniform load), then 1024 batch elems
// stream through a memory-free FMA loop. Grid 16x16x8 = 2048 waves = 8/CU
// at 2 waves/SIMD (VGPR-capped). Partials [o*16+i][b] in d_ws; small reduce
// kernel sums 16 i-partials + b2. Target: ~5us VALU floor for the main loop.

#define BATCH   8192
#define IN_DIM  16
#define OUT_DIM 16
#define H0      16
#define H1      8
#define D0      (IN_DIM * OUT_DIM * H0)   // 4096
#define D1      (IN_DIM * OUT_DIM * H1)   // 2048
#define PACK_STRIDE 192

// ws layout (floats):
//   pack    at 0        : 256 slots x 192           (196,608 B)
//   xT      at 49152    : [16][8192]                (524,288 B)
//   partial at 180224   : [256][8192]  row = o*16+i (8,388,608 B)
#define WS_XT      49152
#define WS_PARTIAL 180224

// Packed slot layout, slot = o*16+i (j = i*16+o):
//   [0..15] W0 col-i | [16..31] b0 | [32..159] W1 (m-major 8x16)
//   [160..167] b1 | [168..175] W2
__global__ void pack_kernel(const float* __restrict__ W0, const float* __restrict__ b0,
                            const float* __restrict__ W1, const float* __restrict__ b1,
                            const float* __restrict__ W2, float* __restrict__ pack)
{
    const int oi = blockIdx.x;            // o*16 + i
    const int o  = oi >> 4, i = oi & 15;
    const int j  = i * 16 + o;
    const int t  = threadIdx.x;
    float val = 0.0f;
    if      (t < 16)  val = W0[(j * H0 + t) * IN_DIM + i];
    else if (t < 32)  val = b0[j * H0 + (t - 16)];
    else if (t < 160) { const int m = (t - 32) >> 4, k = (t - 32) & 15;
                        val = W1[(size_t)(j * H1 + m) * D0 + j * H0 + k]; }
    else if (t < 168) val = b1[j * H1 + (t - 160)];
    else if (t < 176) val = W2[o * D1 + j * H1 + (t - 168)];
    if (t < 176) pack[oi * PACK_STRIDE + t] = val;
}

__global__ void transpose_x(const float* __restrict__ x, float* __restrict__ xT)
{
    const int idx = blockIdx.x * 256 + threadIdx.x;   // 0..131071
    const int i   = idx >> 13;                        // 0..15
    const int b   = idx & 8191;
    xT[idx] = x[(size_t)b * IN_DIM + i];              // write coalesced
}

__global__ __launch_bounds__(64, 2) void mlp_main(
    const float* __restrict__ pack,
    const float* __restrict__ xT,
    float* __restrict__ partial)
{
    const int lane = threadIdx.x;         // 0..63
    const int c    = blockIdx.x;          // batch chunk 0..7
    const int i    = blockIdx.y;
    const int o    = blockIdx.z;
    const int slot = o * 16 + i;

    // ---- one-time: weights -> registers (uniform addresses) ----
    const float* __restrict__ wp = pack + slot * PACK_STRIDE;
    float w0[16], bb0[16], w1[128], bb1[8], w2[8];
    #pragma unroll
    for (int r = 0; r < 16; ++r)  w0[r]  = wp[r];
    #pragma unroll
    for (int r = 0; r < 16; ++r)  bb0[r] = wp[16 + r];
    #pragma unroll
    for (int r = 0; r < 128; ++r) w1[r]  = wp[32 + r];
    #pragma unroll
    for (int r = 0; r < 8; ++r)   bb1[r] = wp[160 + r];
    #pragma unroll
    for (int r = 0; r < 8; ++r)   w2[r]  = wp[168 + r];

    const float* __restrict__ xp = xT + i * BATCH + c * 1024 + lane;
    float* __restrict__ pp = partial + (size_t)slot * BATCH + c * 1024 + lane;

    // ---- memory-free compute loop: 16 iters x 64 batch ----
    #pragma unroll 4
    for (int t = 0; t < 16; ++t) {
        const float xi = xp[t * 64];
        float v[H0];
        #pragma unroll
        for (int k = 0; k < H0; ++k)
            v[k] = fmaxf(fmaf(w0[k], xi, bb0[k]), 0.0f);
        float acc = 0.0f;
        #pragma unroll
        for (int m = 0; m < H1; ++m) {
            float u = bb1[m];
            #pragma unroll
            for (int k = 0; k < H0; ++k)
                u = fmaf(w1[m * 16 + k], v[k], u);
            acc = fmaf(w2[m], fmaxf(u, 0.0f), acc);
        }
        pp[t * 64] = acc;
    }
}

__global__ void reduce_out(const float* __restrict__ partial,
                           const float* __restrict__ b2,
                           float* __restrict__ out)
{
    const int o = blockIdx.y;
    const int b = blockIdx.x * 256 + threadIdx.x;
    float s = b2[o];
    #pragma unroll
    for (int i = 0; i < 16; ++i)
        s += partial[(size_t)(o * 16 + i) * BATCH + b];   // coalesced per i
    out[(size_t)b * OUT_DIM + o] = s;
}

extern "C" void kernel_launch(void* const* d_in, const int* in_sizes, int n_in,
                              void* d_out, int out_size, void* d_ws, size_t ws_size,
                              hipStream_t stream) {
    const float* x  = (const float*)d_in[0];
    const float* W0 = (const float*)d_in[1];
    const float* b0 = (const float*)d_in[2];
    const float* W1 = (const float*)d_in[3];
    const float* b1 = (const float*)d_in[4];
    const float* W2 = (const float*)d_in[5];
    const float* b2 = (const float*)d_in[6];
    float* out  = (float*)d_out;
    float* ws   = (float*)d_ws;

    float* pack    = ws;
    float* xT      = ws + WS_XT;
    float* partial = ws + WS_PARTIAL;

    pack_kernel<<<256, 192, 0, stream>>>(W0, b0, W1, b1, W2, pack);
    transpose_x<<<512, 256, 0, stream>>>(x, xT);

    dim3 mg(8, 16, 16);                    // c, i, o -> 2048 single-wave blocks
    mlp_main<<<mg, 64, 0, stream>>>(pack, xT, partial);

    dim3 rg(BATCH / 256, OUT_DIM);
    reduce_out<<<rg, 256, 0, stream>>>(partial, b2, out);
}

// Round 7
// 97.247 us; speedup vs baseline: 1.2036x; 1.2036x over previous
//
#include <hip/hip_runtime.h>

// SparseNeuralNetwork: 256 independent sub-nets j = i*16 + o (i,o in [0,16)).
//   layer0: v[k] = relu(W0[16j+k, i] * x[b,i] + b0[16j+k]),   k in [0,16)
//   layer1: u[m] = relu(b1[8j+m] + sum_k W1[8j+m, 16j+k] * v[k]), m in [0,8)
//   out[b,o] = b2[o] + sum_i sum_m W2[o, 8j+m] * u[m]
//
// R7: lane = one sub-net j, weights private in VGPRs (one-time 44 coalesced
// float4 loads from a transposed pack), batch streams through a fully
// register-resident FMA loop. Wave = 16 i x 4 o -> i-reduction is a 4-step
// shfl_xor butterfly, output written directly (no partial buffer / reduce
// kernel). Grid 2048 waves = 2/SIMD exactly (VGPR ~218 under the 256 cap).
// R6 failed on VGPR spill (176+unroll4*18 > 256) + 4-launch overhead; this
// keeps live set ~218 and uses 2 launches.

#define BATCH   8192
#define IN_DIM  16
#define OUT_DIM 16
#define H0      16
#define H1      8
#define D0      (IN_DIM * OUT_DIM * H0)   // 4096
#define D1      (IN_DIM * OUT_DIM * H1)   // 2048
#define NR      176                        // live weights per sub-net

// packT layout (floats): element r (0..175) of slot s (0..255) lives at
//   ((r>>2)*256 + s)*4 + (r&3)   -> lane reads float4 row r4 at [r4*256 + s]
// slot s <-> (og = s>>6, lane l = s&63): i = l>>2, o = og*4 + (l&3), j = i*16+o
__global__ void prep_kernel(const float* __restrict__ W0, const float* __restrict__ b0,
                            const float* __restrict__ W1, const float* __restrict__ b1,
                            const float* __restrict__ W2, float* __restrict__ packT)
{
    const int t = blockIdx.x * 256 + threadIdx.x;   // 0..45055
    const int r = ((t >> 10) << 2) | (t & 3);       // 0..175
    const int s = (t >> 2) & 255;
    const int i = (s & 63) >> 2;
    const int o = ((s >> 6) << 2) | (s & 3);
    const int j = i * 16 + o;
    float val;
    if      (r < 16)  val = W0[(j * H0 + r) * IN_DIM + i];
    else if (r < 32)  val = b0[j * H0 + (r - 16)];
    else if (r < 160) { const int rr = r - 32, m = rr >> 4, k = rr & 15;
                        val = W1[(size_t)(j * H1 + m) * D0 + j * H0 + k]; }
    else if (r < 168) val = b1[j * H1 + (r - 160)];
    else              val = W2[o * D1 + j * H1 + (r - 168)];
    packT[t] = val;                                  // coalesced write
}

__global__ __launch_bounds__(64, 2) void mlp_main(
    const float* __restrict__ packT,
    const float* __restrict__ x,
    const float* __restrict__ b2,
    float* __restrict__ out)
{
    const int l   = threadIdx.x;            // 0..63
    const int bx  = blockIdx.x;             // 0..2047
    const int og  = bx & 3;                 // o-group (4 o's per wave)
    const int bb  = (bx >> 2) << 4;         // batch base, 16 elems per wave

    // ---- one-time: this lane's 176 weights -> VGPRs (44 coalesced float4) ----
    float w[NR];
    const float4* __restrict__ wp = (const float4*)packT + og * 64 + l;
    #pragma unroll
    for (int r = 0; r < 44; ++r) {
        const float4 q = wp[r * 256];
        w[4*r] = q.x; w[4*r+1] = q.y; w[4*r+2] = q.z; w[4*r+3] = q.w;
    }

    // ---- x preload: this lane's input column i, 16 batch elems ----
    const int i = l >> 2;
    float xi[16];
    const float* __restrict__ xp = x + (size_t)bb * IN_DIM + i;
    #pragma unroll
    for (int b = 0; b < 16; ++b) xi[b] = xp[b * IN_DIM];

    const float b2v = b2[og * 4 + (l & 3)];

    // ---- register-resident compute, 16 batch elems ----
    #pragma unroll
    for (int b = 0; b < 16; ++b) {
        float v[H0];
        #pragma unroll
        for (int k = 0; k < H0; ++k)
            v[k] = fmaxf(fmaf(w[k], xi[b], w[16 + k]), 0.0f);

        float acc = 0.0f;
        #pragma unroll
        for (int m = 0; m < H1; ++m) {
            float u = w[160 + m];
            #pragma unroll
            for (int k = 0; k < H0; ++k)
                u = fmaf(w[32 + m * 16 + k], v[k], u);
            acc = fmaf(w[168 + m], fmaxf(u, 0.0f), acc);
        }

        // butterfly over i (lane bits 2..5); lanes 0..3 end with full sums
        acc += __shfl_xor(acc, 4, 64);
        acc += __shfl_xor(acc, 8, 64);
        acc += __shfl_xor(acc, 16, 64);
        acc += __shfl_xor(acc, 32, 64);
        if (l < 4)
            out[(size_t)(bb + b) * OUT_DIM + og * 4 + l] = acc + b2v;
    }
}

extern "C" void kernel_launch(void* const* d_in, const int* in_sizes, int n_in,
                              void* d_out, int out_size, void* d_ws, size_t ws_size,
                              hipStream_t stream) {
    const float* x  = (const float*)d_in[0];
    const float* W0 = (const float*)d_in[1];
    const float* b0 = (const float*)d_in[2];
    const float* W1 = (const float*)d_in[3];
    const float* b1 = (const float*)d_in[4];
    const float* W2 = (const float*)d_in[5];
    const float* b2 = (const float*)d_in[6];
    float* out   = (float*)d_out;
    float* packT = (float*)d_ws;            // 176*256*4 = 180,224 B

    prep_kernel<<<176, 256, 0, stream>>>(W0, b0, W1, b1, W2, packT);

    // 2048 blocks x 1 wave: og = bx&3, batch chunk = bx>>2 (16 elems each)
    mlp_main<<<2048, 64, 0, stream>>>(packT, x, b2, out);
}